// Round 1
// baseline (32.239 us; speedup 1.0000x reference)
//
#include <hip/hip_runtime.h>

// Problem constants
#define BB 4
#define LL 512
#define WW 256
#define EE 300
#define HH 768

typedef __attribute__((ext_vector_type(8))) short bf16x8;
typedef __attribute__((ext_vector_type(4))) float f32x4;

__device__ __forceinline__ short f2bf(float f) {
    union { float f; unsigned u; } v; v.f = f;
    unsigned r = (v.u + 0x7FFFu + ((v.u >> 16) & 1u)) >> 16;
    return (short)r;
}

// ---------------------------------------------------------------------------
// K1: a[g][h] = emb_a[word_seq[g]] @ lin_w + lin_b   (g = b*256+w, bf16 out)
// Tile: [64 m x 64 n], K=300 padded to 320, 256 threads (4 waves, each a
// 16-row m-strip). Both LDS tiles stored row-major K-contiguous with padded
// stride 40 shorts (80B -> bank-spread, 16B-aligned).
// ---------------------------------------------------------------------------
__global__ __launch_bounds__(256) void k1_a_gemm(
    const int*   __restrict__ word_seq,  // [1024]
    const float* __restrict__ emb_a,     // [30000][300]
    const float* __restrict__ lin_w,     // [300][768]
    const float* __restrict__ lin_b,     // [768]
    short*       __restrict__ a_g)       // [1024][768] bf16
{
    __shared__ short ea[64 * 40];   // [m-row][k] bf16
    __shared__ short lw[64 * 40];   // [n-row(h)][k] bf16 (transposed stage)
    __shared__ int   word[64];

    const int t  = threadIdx.x;
    const int m0 = blockIdx.x * 64;
    const int n0 = blockIdx.y * 64;

    if (t < 64) word[t] = word_seq[m0 + t];
    __syncthreads();

    const int lane = t & 63, wv = t >> 6;
    const int l15 = lane & 15, l4 = lane >> 4;

    // staging coords
    const int r_ea  = t >> 2;          // 0..63  (m-row)
    const int ec    = (t & 3) * 8;     // k-chunk within 32
    const int h_lw  = t & 63;          // 0..63  (n-row)
    const int kc_lw = (t >> 6) * 8;    // k-chunk within 32

    f32x4 acc[4] = {};

    for (int e0 = 0; e0 < 320; e0 += 32) {
        // ---- stage ea tile [64][32]
        {
            const long base = (long)word[r_ea] * EE + e0 + ec;
            float vals[8];
#pragma unroll
            for (int j = 0; j < 8; j += 2) {
                const int e = e0 + ec + j;          // always even
                if (e < EE) {
                    const float2 p = *(const float2*)(emb_a + base + j);
                    vals[j] = p.x; vals[j + 1] = p.y;
                } else {
                    vals[j] = 0.f; vals[j + 1] = 0.f;
                }
            }
            bf16x8 sv;
#pragma unroll
            for (int j = 0; j < 8; ++j) sv[j] = f2bf(vals[j]);
            *(bf16x8*)(&ea[r_ea * 40 + ec]) = sv;
        }
        // ---- stage lin_w tile transposed -> [h][k]
        {
            bf16x8 sv;
#pragma unroll
            for (int j = 0; j < 8; ++j) {
                const int e = e0 + kc_lw + j;
                const float v = (e < EE) ? lin_w[(long)e * HH + n0 + h_lw] : 0.f;
                sv[j] = f2bf(v);
            }
            *(bf16x8*)(&lw[h_lw * 40 + kc_lw]) = sv;
        }
        __syncthreads();
        // ---- MFMA: wave wv owns m-rows [wv*16, wv*16+16)
        {
            const bf16x8 af = *(const bf16x8*)(&ea[(wv * 16 + l15) * 40 + l4 * 8]);
#pragma unroll
            for (int nf = 0; nf < 4; ++nf) {
                const bf16x8 bfv = *(const bf16x8*)(&lw[(nf * 16 + l15) * 40 + l4 * 8]);
                acc[nf] = __builtin_amdgcn_mfma_f32_16x16x32_bf16(af, bfv, acc[nf], 0, 0, 0);
            }
        }
        __syncthreads();
    }

    // ---- epilogue: bias + bf16 store. D: col = l&15, row = (l>>4)*4 + i
#pragma unroll
    for (int nf = 0; nf < 4; ++nf) {
        const int h    = n0 + nf * 16 + l15;
        const float bv = lin_b[h];
#pragma unroll
        for (int i = 0; i < 4; ++i) {
            const int m = m0 + wv * 16 + l4 * 4 + i;
            a_g[(long)m * HH + h] = f2bf(acc[nf][i] + bv);
        }
    }
}

// ---------------------------------------------------------------------------
// K2: per (b, 16-l-row tile): u = hidden_tile @ a_b^T (MFMA, K=768 in 12
// chunks of 64), exp(u/temper)*mask, label-bucket sums s[c], fused output
// o = (sum_c s_c * emb_c[c]) / (sum_c s_c + 1e-10).
// 256 threads = 4 waves; wave wv owns w-cols [wv*64, wv*64+64) (4 n-frags).
// ---------------------------------------------------------------------------
__global__ __launch_bounds__(256) void k2_attn(
    const float* __restrict__ hidden,   // [4][512][768]
    const int*   __restrict__ label,    // [4][512][256]
    const short* __restrict__ a_g,      // [1024][768] bf16 (row = b*256+w)
    const float* __restrict__ emb_c,    // [6][768]
    float*       __restrict__ out)      // [4][512][768]
{
    __shared__ short hid[16 * 776];     // [l-row][h] bf16, padded stride
    __shared__ short at [256 * 72];     // [w-row][64 h chunk] bf16, padded stride
    __shared__ float s_part[4][16][5];
    __shared__ float s_fin[16][5];
    __shared__ float invd[16];

    const int t   = threadIdx.x;
    const int bl0 = blockIdx.x * 16;       // flat (b*512 + l) row base
    const int b   = bl0 >> 9;
    const int lane = t & 63, wv = t >> 6;
    const int l15 = lane & 15, l4 = lane >> 4;

    // ---- stage hidden tile -> bf16 LDS
    {
        const float* hrow = hidden + (long)bl0 * HH;
#pragma unroll
        for (int r = 0; r < 16; ++r) {
#pragma unroll
            for (int q = 0; q < 3; ++q) {
                const int h = t + q * 256;
                hid[r * 776 + h] = f2bf(hrow[(long)r * HH + h]);
            }
        }
    }
    __syncthreads();

    f32x4 acc[4] = {};
    const short* a_base = a_g + (long)b * 256 * HH;

    for (int kc = 0; kc < 12; ++kc) {
        const int h0 = kc * 64;
        // ---- stage a chunk [256 w][64 h]
#pragma unroll
        for (int p = 0; p < 8; ++p) {
            const int wr = (t >> 3) + 32 * p;
            const int cc = (t & 7) * 8;
            const bf16x8 v = *(const bf16x8*)(a_base + (long)wr * HH + h0 + cc);
            *(bf16x8*)(&at[wr * 72 + cc]) = v;
        }
        __syncthreads();
#pragma unroll
        for (int ks = 0; ks < 2; ++ks) {
            const bf16x8 af = *(const bf16x8*)(&hid[l15 * 776 + h0 + ks * 32 + l4 * 8]);
#pragma unroll
            for (int nf = 0; nf < 4; ++nf) {
                const int wrow = wv * 64 + nf * 16 + l15;
                const bf16x8 bfv = *(const bf16x8*)(&at[wrow * 72 + ks * 32 + l4 * 8]);
                acc[nf] = __builtin_amdgcn_mfma_f32_16x16x32_bf16(af, bfv, acc[nf], 0, 0, 0);
            }
        }
        __syncthreads();
    }

    // ---- exp + masked label-bucket accumulation (static indexing only)
    const float inv_temper = 0.03608439182435161f;   // 1/sqrt(768)
    float s_loc[4][5];
#pragma unroll
    for (int i = 0; i < 4; ++i)
#pragma unroll
        for (int c = 0; c < 5; ++c) s_loc[i][c] = 0.f;

    const int* lab_base = label + (long)bl0 * WW;
#pragma unroll
    for (int nf = 0; nf < 4; ++nf) {
        const int w = wv * 64 + nf * 16 + l15;
#pragma unroll
        for (int i = 0; i < 4; ++i) {
            const int row = l4 * 4 + i;
            const int lv  = lab_base[row * WW + w];
            const float e = __expf(acc[nf][i] * inv_temper);
#pragma unroll
            for (int c = 1; c <= 5; ++c)
                s_loc[i][c - 1] += (lv == c) ? e : 0.f;
        }
    }
    // reduce across the 16 lanes (w-index) sharing the same l4 group
#pragma unroll
    for (int i = 0; i < 4; ++i) {
#pragma unroll
        for (int c = 0; c < 5; ++c) {
            float v = s_loc[i][c];
            v += __shfl_xor(v, 1);
            v += __shfl_xor(v, 2);
            v += __shfl_xor(v, 4);
            v += __shfl_xor(v, 8);
            s_loc[i][c] = v;
        }
    }
    if (l15 == 0) {
#pragma unroll
        for (int i = 0; i < 4; ++i)
#pragma unroll
            for (int c = 0; c < 5; ++c)
                s_part[wv][l4 * 4 + i][c] = s_loc[i][c];
    }
    __syncthreads();
    if (t < 16) {
        float den = 0.f;
#pragma unroll
        for (int c = 0; c < 5; ++c) {
            const float s = s_part[0][t][c] + s_part[1][t][c] +
                            s_part[2][t][c] + s_part[3][t][c];
            s_fin[t][c] = s;
            den += s;
        }
        invd[t] = 1.0f / (den + 1e-10f);
    }
    __syncthreads();

    // ---- fused output: o[row][h] = invd * sum_c s_c * emb_c[c][h]
    float ecv[3][5];
#pragma unroll
    for (int q = 0; q < 3; ++q)
#pragma unroll
        for (int c = 0; c < 5; ++c)
            ecv[q][c] = emb_c[(c + 1) * HH + t + q * 256];

    float* obase = out + (long)bl0 * HH;
    for (int row = 0; row < 16; ++row) {
        const float id = invd[row];
        const float s0 = s_fin[row][0], s1 = s_fin[row][1], s2 = s_fin[row][2],
                    s3 = s_fin[row][3], s4 = s_fin[row][4];
#pragma unroll
        for (int q = 0; q < 3; ++q) {
            const float v = s0 * ecv[q][0] + s1 * ecv[q][1] + s2 * ecv[q][2] +
                            s3 * ecv[q][3] + s4 * ecv[q][4];
            obase[(long)row * HH + t + q * 256] = v * id;
        }
    }
}

extern "C" void kernel_launch(void* const* d_in, const int* in_sizes, int n_in,
                              void* d_out, int out_size, void* d_ws, size_t ws_size,
                              hipStream_t stream) {
    const int*   word_seq = (const int*)  d_in[0];
    const float* hidden   = (const float*)d_in[1];
    const int*   label    = (const int*)  d_in[2];
    const float* emb_a    = (const float*)d_in[3];
    const float* lin_w    = (const float*)d_in[4];
    const float* lin_b    = (const float*)d_in[5];
    const float* emb_c    = (const float*)d_in[6];
    float* out = (float*)d_out;
    short* a_g = (short*)d_ws;   // 1024*768*2 = 1.5 MB scratch

    k1_a_gemm<<<dim3(16, 12), 256, 0, stream>>>(word_seq, emb_a, lin_w, lin_b, a_g);
    k2_attn<<<dim3(128), 256, 0, stream>>>(hidden, label, a_g, emb_c, out);
}